// Round 12
// baseline (128.094 us; speedup 1.0000x reference)
//
#include <hip/hip_runtime.h>
#include <hip/hip_bf16.h>

// GraphAttentionLayer fused kernels for MI355X (gfx950).
// N=8192, IN=512, OUT=64. adj read (256MB @ ~6.9TB/s) => ~37us floor.
// r12: pack fused INTO attn as a bulk phase (per-wave vmcnt FIFO isolation:
// phase 1 = only adj loads; sync; phase 2 = only L2 loads + MFMA). No global
// bitmask buffer, one fewer dispatch, no 8MB round-trip.
//  K1 wh (256 blocks): Wh=h@W fp32, WhbT bf16 [64][8192] transposed,
//     Wh1L/W2L rank-1 log2-scaled score vectors (r8 form, unchanged).
//  K2 attn (256 blocks x 512 thr): phase 1 streams 32 adj rows -> bm_lds bits
//     (int4 loads, nibble pack + 3-level shfl_xor merge, r11-verified);
//     phase 2 = r10/r11 loop: p=2^lrelu(wh1+w2) masked, bf16 cvt_pk, 4+1
//     MFMA (ones-MFMA denominators), 2 row-groups share bf frags; epilogue
//     cross-wave sum + normalize + ELU.

#define LOG2E 1.4426950408889634f

typedef __attribute__((ext_vector_type(8))) short  short8v;
typedef __attribute__((ext_vector_type(8))) unsigned short ushort8v;
typedef __attribute__((ext_vector_type(4))) float  f32x4;

__device__ __forceinline__ unsigned short f2bf(float f) {
    union { float f; unsigned int u; } x; x.f = f;
    unsigned int r = x.u + 0x7FFFu + ((x.u >> 16) & 1u);   // RNE
    return (unsigned short)(r >> 16);
}

// ---------------- Kernel 1: wh (r8 form, unchanged) ----------------
__global__ __launch_bounds__(256) void wh_kernel(
        const float* __restrict__ h, const float* __restrict__ W,
        const float* __restrict__ a,
        unsigned short* __restrict__ WhbT,
        float* __restrict__ Wh1L, float* __restrict__ W2L) {
    const int wave = threadIdx.x >> 6;
    const int lane = threadIdx.x & 63;
    const int row0 = (blockIdx.x * 4 + wave) * 8;

    float acc[8];
#pragma unroll
    for (int rr = 0; rr < 8; ++rr) acc[rr] = 0.f;

    const float* hrow = h + (size_t)row0 * 512;
    for (int i = 0; i < 512; i += 4) {
        float w0 = W[(i + 0) * 64 + lane];
        float w1 = W[(i + 1) * 64 + lane];
        float w2 = W[(i + 2) * 64 + lane];
        float w3 = W[(i + 3) * 64 + lane];
#pragma unroll
        for (int rr = 0; rr < 8; ++rr) {
            float4 hv = *reinterpret_cast<const float4*>(hrow + (size_t)rr * 512 + i);
            acc[rr] = fmaf(hv.x, w0, fmaf(hv.y, w1, fmaf(hv.z, w2, fmaf(hv.w, w3, acc[rr]))));
        }
    }

    ushort8v bt;
#pragma unroll
    for (int rr = 0; rr < 8; ++rr) bt[rr] = f2bf(acc[rr]);
    *reinterpret_cast<ushort8v*>(WhbT + (size_t)lane * 8192 + row0) = bt;

    const float a1 = a[lane] * LOG2E, a2 = a[lane + 64] * LOG2E;
#pragma unroll
    for (int rr = 0; rr < 8; ++rr) {
        float t1 = acc[rr] * a1;
        float t2 = acc[rr] * a2;
#pragma unroll
        for (int off = 32; off; off >>= 1) {
            t1 += __shfl_xor(t1, off);
            t2 += __shfl_xor(t2, off);
        }
        if (lane == 0) { Wh1L[row0 + rr] = t1; W2L[row0 + rr] = t2; }
    }
}

// ---------------- Kernel 2: fused pack + mask + softmax + PV ----------------
// grid 256 x 512 (8 waves). Block: 32 rows x 8192 cols.
__global__ __launch_bounds__(512) void attn_kernel(
        const int* __restrict__ adj,
        const unsigned short* __restrict__ WhbT,
        const float* __restrict__ Wh1L, const float* __restrict__ W2L,
        float* __restrict__ out) {
    __shared__ unsigned int bm_lds[32][260];   // 33.3KB
    __shared__ float sm_acc[8][64][17];        // 34.8KB, padded
    __shared__ float sm_l[8][2][16];           // 1KB

    const int tid  = threadIdx.x;
    const int w    = tid >> 6;
    const int lane = tid & 63;
    const int fr   = lane & 15;      // MFMA row (A) / col (B,D)
    const int cg   = lane >> 4;      // k-group
    const int i0   = blockIdx.x * 32;

    // ---- phase 1: stream adj rows -> bitmask in LDS (only adj in VM FIFO) ----
    {
        const int r0 = w * 4;                      // wave packs rows r0..r0+3
        const int* ap0 = adj + (size_t)(i0 + r0 + 0) * 8192 + lane * 4;
        const int* ap1 = adj + (size_t)(i0 + r0 + 1) * 8192 + lane * 4;
        const int* ap2 = adj + (size_t)(i0 + r0 + 2) * 8192 + lane * 4;
        const int* ap3 = adj + (size_t)(i0 + r0 + 3) * 8192 + lane * 4;
        for (int it = 0; it < 32; ++it) {
            int4 v[4];
            v[0] = *reinterpret_cast<const int4*>(ap0 + it * 256);
            v[1] = *reinterpret_cast<const int4*>(ap1 + it * 256);
            v[2] = *reinterpret_cast<const int4*>(ap2 + it * 256);
            v[3] = *reinterpret_cast<const int4*>(ap3 + it * 256);
#pragma unroll
            for (int rr = 0; rr < 4; ++rr) {
                unsigned int n = (unsigned int)(v[rr].x > 0)
                               | ((unsigned int)(v[rr].y > 0) << 1)
                               | ((unsigned int)(v[rr].z > 0) << 2)
                               | ((unsigned int)(v[rr].w > 0) << 3);
                n |= ((unsigned int)__shfl_xor((int)n, 1)) << 4;
                n |= ((unsigned int)__shfl_xor((int)n, 2)) << 8;
                n |= ((unsigned int)__shfl_xor((int)n, 4)) << 16;
                if ((lane & 7) == 0) bm_lds[r0 + rr][it * 8 + (lane >> 3)] = n;
            }
        }
    }
    __syncthreads();

    // ---- phase 2: masked softmax numerators + PV (only L2 loads in FIFO) ----
    const float wh1a = Wh1L[i0 + fr];
    const float wh1b = Wh1L[i0 + 16 + fr];

    f32x4 acc[2][4];
#pragma unroll
    for (int rg = 0; rg < 2; ++rg)
#pragma unroll
        for (int f = 0; f < 4; ++f) acc[rg][f] = (f32x4){0.f, 0.f, 0.f, 0.f};
    f32x4 accl[2];
    accl[0] = (f32x4){0.f, 0.f, 0.f, 0.f};
    accl[1] = (f32x4){0.f, 0.f, 0.f, 0.f};

    short8v ones;
#pragma unroll
    for (int b = 0; b < 8; ++b) ones[b] = (short)0x3F80;   // bf16 1.0

    const float*          w2p = W2L + w * 32 + cg * 8;
    const unsigned short* bfp = WhbT + (size_t)fr * 8192 + w * 32 + cg * 8;
    const int sh = cg * 8;

    for (int it = 0; it < 32; ++it) {
        const int cbase = it * 256;
        float4 W0 = *reinterpret_cast<const float4*>(w2p + cbase);
        float4 W1 = *reinterpret_cast<const float4*>(w2p + cbase + 4);
        short8v bf[4];
#pragma unroll
        for (int f = 0; f < 4; ++f)
            bf[f] = *reinterpret_cast<const short8v*>(bfp + (size_t)f * 16 * 8192 + cbase);

        const int wi = it * 8 + w;
        const unsigned int wd0 = bm_lds[fr][wi];
        const unsigned int wd1 = bm_lds[16 + fr][wi];

#pragma unroll
        for (int rg = 0; rg < 2; ++rg) {
            const unsigned int wd  = rg ? wd1 : wd0;
            const float        wh1 = rg ? wh1b : wh1a;
            float p[8]; float t;
            t = wh1 + W0.x; t = fmaxf(t, 0.2f * t); p[0] = ((wd >> (sh + 0)) & 1u) ? __builtin_exp2f(t) : 0.f;
            t = wh1 + W0.y; t = fmaxf(t, 0.2f * t); p[1] = ((wd >> (sh + 1)) & 1u) ? __builtin_exp2f(t) : 0.f;
            t = wh1 + W0.z; t = fmaxf(t, 0.2f * t); p[2] = ((wd >> (sh + 2)) & 1u) ? __builtin_exp2f(t) : 0.f;
            t = wh1 + W0.w; t = fmaxf(t, 0.2f * t); p[3] = ((wd >> (sh + 3)) & 1u) ? __builtin_exp2f(t) : 0.f;
            t = wh1 + W1.x; t = fmaxf(t, 0.2f * t); p[4] = ((wd >> (sh + 4)) & 1u) ? __builtin_exp2f(t) : 0.f;
            t = wh1 + W1.y; t = fmaxf(t, 0.2f * t); p[5] = ((wd >> (sh + 5)) & 1u) ? __builtin_exp2f(t) : 0.f;
            t = wh1 + W1.z; t = fmaxf(t, 0.2f * t); p[6] = ((wd >> (sh + 6)) & 1u) ? __builtin_exp2f(t) : 0.f;
            t = wh1 + W1.w; t = fmaxf(t, 0.2f * t); p[7] = ((wd >> (sh + 7)) & 1u) ? __builtin_exp2f(t) : 0.f;

            union { short8v s8; __hip_bfloat162 h2[4]; } u;
            u.h2[0] = __float22bfloat162_rn(float2{p[0], p[1]});
            u.h2[1] = __float22bfloat162_rn(float2{p[2], p[3]});
            u.h2[2] = __float22bfloat162_rn(float2{p[4], p[5]});
            u.h2[3] = __float22bfloat162_rn(float2{p[6], p[7]});

#pragma unroll
            for (int f = 0; f < 4; ++f)
                acc[rg][f] = __builtin_amdgcn_mfma_f32_16x16x32_bf16(u.s8, bf[f], acc[rg][f], 0, 0, 0);
            accl[rg] = __builtin_amdgcn_mfma_f32_16x16x32_bf16(u.s8, ones, accl[rg], 0, 0, 0);
        }
    }

    // ---- epilogue: cross-wave sums, normalize, ELU ----
#pragma unroll
    for (int rg = 0; rg < 2; ++rg) {
        __syncthreads();
#pragma unroll
        for (int f = 0; f < 4; ++f)
#pragma unroll
            for (int reg = 0; reg < 4; ++reg)
                sm_acc[w][lane][f * 4 + reg] = acc[rg][f][reg];
        if (fr == 0) {
#pragma unroll
            for (int reg = 0; reg < 4; ++reg) sm_l[w][rg][4 * cg + reg] = accl[rg][reg];
        }
        __syncthreads();

#pragma unroll
        for (int ss = 0; ss < 2; ++ss) {
            const int s = 2 * w + ss;
            const int f = s >> 2, reg = s & 3;
            float sum = 0.f;
#pragma unroll
            for (int ww = 0; ww < 8; ++ww) sum += sm_acc[ww][lane][s];
            const int R = 4 * cg + reg;
            float lrow = 0.f;
#pragma unroll
            for (int ww = 0; ww < 8; ++ww) lrow += sm_l[ww][rg][R];
            float y = sum / lrow;
            y = y > 0.f ? y : expm1f(y);          // ELU, alpha=1
            out[(size_t)(i0 + rg * 16 + R) * 64 + 16 * f + fr] = y;
        }
    }
}

extern "C" void kernel_launch(void* const* d_in, const int* in_sizes, int n_in,
                              void* d_out, int out_size, void* d_ws, size_t ws_size,
                              hipStream_t stream) {
    const float* h   = (const float*)d_in[0];
    const int*   adj = (const int*)d_in[1];
    const float* W   = (const float*)d_in[2];
    const float* a   = (const float*)d_in[3];

    unsigned short* WhbT = (unsigned short*)d_ws;                    // 1 MB
    float*          Wh1L = (float*)((char*)d_ws + (1 << 20));        // 32 KB
    float*          W2L  = Wh1L + 8192;                              // 32 KB

    wh_kernel<<<256, 256, 0, stream>>>(h, W, a, WhbT, Wh1L, W2L);
    attn_kernel<<<256, 512, 0, stream>>>(adj, WhbT, Wh1L, W2L, (float*)d_out);
}